// Round 4
// baseline (243.329 us; speedup 1.0000x reference)
//
#include <hip/hip_runtime.h>

typedef _Float16 v8h __attribute__((ext_vector_type(8)));
typedef _Float16 v4h __attribute__((ext_vector_type(4)));
typedef float    v4f __attribute__((ext_vector_type(4)));

#define MFMA16(a, b, c) __builtin_amdgcn_mfma_f32_16x16x32_f16((a), (b), (c), 0, 0, 0)

// Weight-fragment table in d_ws: 154 fragments, layout [frag][lane] of 8 x f16 (16B).
// Non-zero 32(k) x 16(n) tiles of the 480x480 block-diagonal Wbig:
//   ot 0..7   (cols   0..127): kt 0..3   fbase = ot*4
//   ot 8..19  (cols 128..319): kt 4..9   fbase = 32 + (ot-8)*6
//   ot 20..29 (cols 320..479): kt 10..14 fbase = 104 + (ot-20)*5
// Fragment element convention (consistent for A and B): lane l, elem e holds
// k = kt*32 + (l>>4)*8 + e;  B: n = ot*16 + (l&15);  A: m = l&15.
// C/D (HW-verified): lane l, reg j -> row (l>>4)*4 + j, col l&15.

__global__ void build_frags_k(const float* __restrict__ W0, const float* __restrict__ W1,
                              const float* __restrict__ W2, v8h* __restrict__ frag) {
  const int f = blockIdx.x;
  const int lane = threadIdx.x;
  int ot, kt;
  if (f < 32)       { ot = f >> 2;           kt = f & 3; }
  else if (f < 104) { int q = f - 32;  ot = 8 + q / 6;  kt = 4 + q % 6; }
  else              { int q = f - 104; ot = 20 + q / 5; kt = 10 + q % 5; }
  const int n  = ot * 16 + (lane & 15);
  const int kb = kt * 32 + (lane >> 4) * 8;
  v8h v;
#pragma unroll
  for (int e = 0; e < 8; ++e) {
    const int k = kb + e;
    float wv = 0.0f;
    if (k < 128) {
      if (n < 128) wv = W0[k * 128 + n] * 0.08838834764831845f;           // 1/sqrt(128)
    } else if (k < 320) {
      if (n >= 128 && n < 320) {
        const int i = k - 128, o = n - 128;
        if (i % 3 == o % 3) wv = W1[(i / 3) * 64 + (o / 3)] * 0.125f;     // 1/sqrt(64)
      }
    } else {
      if (n >= 320) {
        const int i = k - 320, o = n - 320;
        if (i % 5 == o % 5) wv = W2[(i / 5) * 32 + (o / 5)] * 0.17677669529663687f; // 1/sqrt(32)
      }
    }
    v[e] = (_Float16)wv;
  }
  frag[f * 64 + lane] = v;
}

// Small independent blocks: 128 threads (2 waves), 16 rows, 16KB LDS.
// Up to 8 blocks/CU resident at staggered phases -> the HBM read stream never
// idles without any explicit pipelining. One barrier per block, then each wave
// handles its ot-parity half of the 30 col-tiles from LDS-held A-fragments.
__global__ __launch_bounds__(128, 4) void irrep_linear_k(
    const float* __restrict__ x, const v8h* __restrict__ frag, float* __restrict__ out) {
  __shared__ __align__(16) unsigned char sm[16 * 1024];
  const int t = threadIdx.x;
  const size_t wt = blockIdx.x;              // 16-row tile index

  // ---- stage: 16 rows x 480 f32, fully coalesced ----
  float4 rg[15];
  {
    const float4* p = reinterpret_cast<const float4*>(x) + wt * 1920;
#pragma unroll
    for (int i = 0; i < 15; ++i) rg[i] = p[i * 128 + t];
  }
#pragma unroll
  for (int i = 0; i < 15; ++i) {
    const int idx = i * 128 + t;             // 0..1919 over the 16x480 tile
    const int r   = idx / 120;               // magic-mul, cheap
    const int c4  = idx - r * 120;
    const unsigned off = (unsigned)r * 1024u + (((unsigned)c4 * 8u) ^ ((unsigned)(r & 7) << 4));
    v4h v;
    v[0] = (_Float16)rg[i].x; v[1] = (_Float16)rg[i].y;
    v[2] = (_Float16)rg[i].z; v[3] = (_Float16)rg[i].w;
    *reinterpret_cast<v4h*>(sm + off) = v;
  }
  __syncthreads();

  const int par  = t >> 6;                   // wave 0/1 -> ot parity
  const int lane = t & 63;
  const int r16  = lane & 15;
  const int g    = lane >> 4;
  const unsigned abase = (unsigned)r16 * 1024u + (unsigned)g * 16u;
  const unsigned swz   = ((unsigned)r16 & 7u) << 4;
  const unsigned char* smc = sm;
#define LDA(kt) (*reinterpret_cast<const v8h*>(smc + ((abase + (unsigned)(kt) * 64u) ^ swz)))

  float* const obase = out + (wt * 16 + (size_t)g * 4) * 480 + r16;

  {  // cols 0..127, K-tiles 0..3
    const v8h a0 = LDA(0), a1 = LDA(1), a2 = LDA(2), a3 = LDA(3);
    for (int ot = par; ot < 8; ot += 2) {
      const v8h* bp = frag + ot * 4 * 64 + lane;
      v4f acc = {0.f, 0.f, 0.f, 0.f};
      acc = MFMA16(a0, bp[0],   acc);
      acc = MFMA16(a1, bp[64],  acc);
      acc = MFMA16(a2, bp[128], acc);
      acc = MFMA16(a3, bp[192], acc);
      float* p = obase + ot * 16;
      __builtin_nontemporal_store(acc[0], p);
      __builtin_nontemporal_store(acc[1], p + 480);
      __builtin_nontemporal_store(acc[2], p + 960);
      __builtin_nontemporal_store(acc[3], p + 1440);
    }
  }
  {  // cols 128..319, K-tiles 4..9
    const v8h a4 = LDA(4), a5 = LDA(5), a6 = LDA(6), a7 = LDA(7), a8 = LDA(8), a9 = LDA(9);
    for (int ot = 8 + par; ot < 20; ot += 2) {
      const v8h* bp = frag + (32 + (ot - 8) * 6) * 64 + lane;
      v4f acc = {0.f, 0.f, 0.f, 0.f};
      acc = MFMA16(a4, bp[0],   acc);
      acc = MFMA16(a5, bp[64],  acc);
      acc = MFMA16(a6, bp[128], acc);
      acc = MFMA16(a7, bp[192], acc);
      acc = MFMA16(a8, bp[256], acc);
      acc = MFMA16(a9, bp[320], acc);
      float* p = obase + ot * 16;
      __builtin_nontemporal_store(acc[0], p);
      __builtin_nontemporal_store(acc[1], p + 480);
      __builtin_nontemporal_store(acc[2], p + 960);
      __builtin_nontemporal_store(acc[3], p + 1440);
    }
  }
  {  // cols 320..479, K-tiles 10..14
    const v8h aA = LDA(10), aB = LDA(11), aC = LDA(12), aD = LDA(13), aE = LDA(14);
    for (int ot = 20 + par; ot < 30; ot += 2) {
      const v8h* bp = frag + (104 + (ot - 20) * 5) * 64 + lane;
      v4f acc = {0.f, 0.f, 0.f, 0.f};
      acc = MFMA16(aA, bp[0],   acc);
      acc = MFMA16(aB, bp[64],  acc);
      acc = MFMA16(aC, bp[128], acc);
      acc = MFMA16(aD, bp[192], acc);
      acc = MFMA16(aE, bp[256], acc);
      float* p = obase + ot * 16;
      __builtin_nontemporal_store(acc[0], p);
      __builtin_nontemporal_store(acc[1], p + 480);
      __builtin_nontemporal_store(acc[2], p + 960);
      __builtin_nontemporal_store(acc[3], p + 1440);
    }
  }
#undef LDA
}

extern "C" void kernel_launch(void* const* d_in, const int* in_sizes, int n_in,
                              void* d_out, int out_size, void* d_ws, size_t ws_size,
                              hipStream_t stream) {
  const float* x  = (const float*)d_in[0];
  const float* W0 = (const float*)d_in[1];
  const float* W1 = (const float*)d_in[2];
  const float* W2 = (const float*)d_in[3];
  float* out = (float*)d_out;
  v8h* frag = (v8h*)d_ws;   // 154 * 64 * 16 B = 157,696 B

  build_frags_k<<<154, 64, 0, stream>>>(W0, W1, W2, frag);

  const int N = in_sizes[0] / 480;      // 200000
  const int nblk = N / 16;              // 12500 tiles, one per block
  irrep_linear_k<<<nblk, 128, 0, stream>>>(x, frag, out);
}

// Round 5
// 189.264 us; speedup vs baseline: 1.2857x; 1.2857x over previous
//
#include <hip/hip_runtime.h>

typedef _Float16 v8h __attribute__((ext_vector_type(8)));
typedef float    v4f __attribute__((ext_vector_type(4)));

#define MFMA16(a, b, c) __builtin_amdgcn_mfma_f32_16x16x32_f16((a), (b), (c), 0, 0, 0)

// Direct global->LDS, 16B per lane per instruction; LDS dest is wave-uniform
// base + lane*16 (HW rule), so LDS stays LINEAR and the bank-swizzle is done
// by permuting the per-lane GLOBAL source address (same involution applied on
// the read side): granule(16B) index j at row r lives at LDS granule j^(r&7)
// within its 128B-aligned group of 8.
#define GLL16(gptr, lptr)                                                        \
  __builtin_amdgcn_global_load_lds((const __attribute__((address_space(1))) void*)(gptr), \
                                   (__attribute__((address_space(3))) void*)(lptr), 16, 0, 0)

// Weight-fragment table in d_ws: 154 fragments, layout [frag][lane] of 8 x f16 (16B).
// Non-zero 32(k) x 16(n) tiles of the 480x480 block-diagonal Wbig:
//   ot 0..7   (cols   0..127): kt 0..3   fbase = ot*4
//   ot 8..19  (cols 128..319): kt 4..9   fbase = 32 + (ot-8)*6
//   ot 20..29 (cols 320..479): kt 10..14 fbase = 104 + (ot-20)*5
// Fragment element convention (consistent for A and B): lane l, elem e holds
// k = kt*32 + (l>>4)*8 + e;  B: n = ot*16 + (l&15);  A: m = l&15.
// C/D (HW-verified): lane l, reg j -> row (l>>4)*4 + j, col l&15.

__global__ void build_frags_k(const float* __restrict__ W0, const float* __restrict__ W1,
                              const float* __restrict__ W2, v8h* __restrict__ frag) {
  const int f = blockIdx.x;
  const int lane = threadIdx.x;
  int ot, kt;
  if (f < 32)       { ot = f >> 2;           kt = f & 3; }
  else if (f < 104) { int q = f - 32;  ot = 8 + q / 6;  kt = 4 + q % 6; }
  else              { int q = f - 104; ot = 20 + q / 5; kt = 10 + q % 5; }
  const int n  = ot * 16 + (lane & 15);
  const int kb = kt * 32 + (lane >> 4) * 8;
  v8h v;
#pragma unroll
  for (int e = 0; e < 8; ++e) {
    const int k = kb + e;
    float wv = 0.0f;
    if (k < 128) {
      if (n < 128) wv = W0[k * 128 + n] * 0.08838834764831845f;           // 1/sqrt(128)
    } else if (k < 320) {
      if (n >= 128 && n < 320) {
        const int i = k - 128, o = n - 128;
        if (i % 3 == o % 3) wv = W1[(i / 3) * 64 + (o / 3)] * 0.125f;     // 1/sqrt(64)
      }
    } else {
      if (n >= 320) {
        const int i = k - 320, o = n - 320;
        if (i % 5 == o % 5) wv = W2[(i / 5) * 32 + (o / 5)] * 0.17677669529663687f; // 1/sqrt(32)
      }
    }
    v[e] = (_Float16)wv;
  }
  frag[f * 64 + lane] = v;
}

// 128 threads (2 waves), 16 rows, 30720B LDS (f32, linear+src-swizzled)
// -> 5 blocks/CU. Staging = 15 global_load_lds per wave: no dest VGPRs, so
// the whole 30KB tile is queued immediately (~150KB outstanding per CU across
// resident blocks) -> HBM read stream never starves. One barrier per block.
__global__ __launch_bounds__(128, 2) void irrep_linear_k(
    const float* __restrict__ x, const v8h* __restrict__ frag, float* __restrict__ out) {
  __shared__ __align__(16) unsigned char sm[30720];
  const int t    = threadIdx.x;
  const int lane = t & 63;
  const int wid  = t >> 6;
  const size_t wt = blockIdx.x;              // 16-row tile index

  // ---- stage: 16 rows x 1920B, direct to LDS with source-side swizzle ----
  {
    const unsigned char* xt = (const unsigned char*)x + wt * 30720u;
#pragma unroll
    for (int i = 0; i < 15; ++i) {
      const unsigned s   = (unsigned)(wid * 15360 + i * 1024 + lane * 16);
      const unsigned r   = s / 1920u;
      const unsigned j   = (s - r * 1920u) >> 4;
      const unsigned jg  = j ^ (r & 7u);     // involution within 128B group
      GLL16(xt + r * 1920u + (jg << 4), sm + (wid * 15360 + i * 1024));
    }
  }
  __syncthreads();   // drains vmcnt for the gll's + lgkm

  const int par = wid;                       // wave -> ot parity
  const int r16 = lane & 15;
  const int g   = lane >> 4;
  const unsigned rb = (unsigned)r16 * 1920u;
  const unsigned q  = (unsigned)(r16 & 7);
  const unsigned char* smc = sm;

  // A-fragment for k-tile kt: lane reads 8 f32 at row r16, cols kt*32+g*8
  // = granules {kt*8+g*2, +1}, each at LDS granule (j ^ q) within its group.
#define LDAF(kt, dst)                                                              \
  {                                                                                \
    const unsigned j0 = (unsigned)((kt) * 8 + g * 2);                              \
    const float4 lo = *reinterpret_cast<const float4*>(smc + rb + ((j0 ^ q) << 4));        \
    const float4 hi = *reinterpret_cast<const float4*>(smc + rb + (((j0 + 1) ^ q) << 4));  \
    v8h v_;                                                                        \
    v_[0] = (_Float16)lo.x; v_[1] = (_Float16)lo.y;                                \
    v_[2] = (_Float16)lo.z; v_[3] = (_Float16)lo.w;                                \
    v_[4] = (_Float16)hi.x; v_[5] = (_Float16)hi.y;                                \
    v_[6] = (_Float16)hi.z; v_[7] = (_Float16)hi.w;                                \
    dst = v_;                                                                      \
  }

  float* const obase = out + (wt * 16 + (size_t)g * 4) * 480 + r16;

  {  // cols 0..127, K-tiles 0..3
    v8h a0, a1, a2, a3;
    LDAF(0, a0) LDAF(1, a1) LDAF(2, a2) LDAF(3, a3)
    for (int ot = par; ot < 8; ot += 2) {
      const v8h* bp = frag + ot * 4 * 64 + lane;
      v4f acc = {0.f, 0.f, 0.f, 0.f};
      acc = MFMA16(a0, bp[0],   acc);
      acc = MFMA16(a1, bp[64],  acc);
      acc = MFMA16(a2, bp[128], acc);
      acc = MFMA16(a3, bp[192], acc);
      float* p = obase + ot * 16;
      p[0] = acc[0]; p[480] = acc[1]; p[960] = acc[2]; p[1440] = acc[3];
    }
  }
  {  // cols 128..319, K-tiles 4..9
    v8h a4, a5, a6, a7, a8, a9;
    LDAF(4, a4) LDAF(5, a5) LDAF(6, a6) LDAF(7, a7) LDAF(8, a8) LDAF(9, a9)
    for (int ot = 8 + par; ot < 20; ot += 2) {
      const v8h* bp = frag + (32 + (ot - 8) * 6) * 64 + lane;
      v4f acc = {0.f, 0.f, 0.f, 0.f};
      acc = MFMA16(a4, bp[0],   acc);
      acc = MFMA16(a5, bp[64],  acc);
      acc = MFMA16(a6, bp[128], acc);
      acc = MFMA16(a7, bp[192], acc);
      acc = MFMA16(a8, bp[256], acc);
      acc = MFMA16(a9, bp[320], acc);
      float* p = obase + ot * 16;
      p[0] = acc[0]; p[480] = acc[1]; p[960] = acc[2]; p[1440] = acc[3];
    }
  }
  {  // cols 320..479, K-tiles 10..14
    v8h aA, aB, aC, aD, aE;
    LDAF(10, aA) LDAF(11, aB) LDAF(12, aC) LDAF(13, aD) LDAF(14, aE)
    for (int ot = 20 + par; ot < 30; ot += 2) {
      const v8h* bp = frag + (104 + (ot - 20) * 5) * 64 + lane;
      v4f acc = {0.f, 0.f, 0.f, 0.f};
      acc = MFMA16(aA, bp[0],   acc);
      acc = MFMA16(aB, bp[64],  acc);
      acc = MFMA16(aC, bp[128], acc);
      acc = MFMA16(aD, bp[192], acc);
      acc = MFMA16(aE, bp[256], acc);
      float* p = obase + ot * 16;
      p[0] = acc[0]; p[480] = acc[1]; p[960] = acc[2]; p[1440] = acc[3];
    }
  }
#undef LDAF
}

extern "C" void kernel_launch(void* const* d_in, const int* in_sizes, int n_in,
                              void* d_out, int out_size, void* d_ws, size_t ws_size,
                              hipStream_t stream) {
  const float* x  = (const float*)d_in[0];
  const float* W0 = (const float*)d_in[1];
  const float* W1 = (const float*)d_in[2];
  const float* W2 = (const float*)d_in[3];
  float* out = (float*)d_out;
  v8h* frag = (v8h*)d_ws;   // 154 * 64 * 16 B = 157,696 B

  build_frags_k<<<154, 64, 0, stream>>>(W0, W1, W2, frag);

  const int N = in_sizes[0] / 480;      // 200000
  const int nblk = N / 16;              // 12500 tiles, one per block
  irrep_linear_k<<<nblk, 128, 0, stream>>>(x, frag, out);
}